// Round 1
// baseline (806.461 us; speedup 1.0000x reference)
//
#include <hip/hip_runtime.h>

#define DIM 128
#define NEG_SLOPE 0.01f

// ---------------- degree / dinv ----------------
__global__ void k_deg(const int* __restrict__ dst, float* __restrict__ deg, int nE) {
    int i = blockIdx.x * blockDim.x + threadIdx.x;
    if (i < nE) atomicAdd(&deg[dst[i]], 1.0f);
}

__global__ void k_dinv(float* __restrict__ deg, int n) {
    int i = blockIdx.x * blockDim.x + threadIdx.x;
    if (i < n) deg[i] = rsqrtf(deg[i] + 1.0f);
}

// ---------------- GEMM: Y[n,128] = X[n,128] @ W[128,128] ----------------
// Block: 256 threads, tile 64 rows x 128 cols, K-tiled by 32.
// Thread (tc = t&31, tr = t>>5) computes rows tr*8..tr*8+7, cols {tc, tc+32, tc+64, tc+96}.
__global__ __launch_bounds__(256) void k_gemm(const float* __restrict__ X,
                                              const float* __restrict__ W,
                                              float* __restrict__ Y, int nRows) {
    __shared__ float sW[32 * 128];  // 16 KB
    __shared__ float sX[64 * 32];   // 8 KB
    const int t = threadIdx.x;
    const int row0 = blockIdx.x * 64;
    const int tc = t & 31;
    const int tr = t >> 5;

    float acc[8][4];
#pragma unroll
    for (int r = 0; r < 8; ++r)
#pragma unroll
        for (int j = 0; j < 4; ++j) acc[r][j] = 0.0f;

    for (int kb = 0; kb < 4; ++kb) {
        __syncthreads();
        // stage W slab: rows kb*32..kb*32+31, 4096 floats = 1024 float4
        for (int i = t; i < 1024; i += 256)
            ((float4*)sW)[i] = ((const float4*)(W + kb * 32 * 128))[i];
        // stage X slab: 64 rows x 32 k = 512 float4
        for (int i = t; i < 512; i += 256) {
            int r = i >> 3, c4 = i & 7;
            int gr = row0 + r;
            float4 v = make_float4(0.f, 0.f, 0.f, 0.f);
            if (gr < nRows) v = *(const float4*)&X[(size_t)gr * 128 + kb * 32 + c4 * 4];
            *(float4*)&sX[r * 32 + c4 * 4] = v;
        }
        __syncthreads();
#pragma unroll
        for (int kk = 0; kk < 32; ++kk) {
            float wv0 = sW[kk * 128 + tc];
            float wv1 = sW[kk * 128 + tc + 32];
            float wv2 = sW[kk * 128 + tc + 64];
            float wv3 = sW[kk * 128 + tc + 96];
#pragma unroll
            for (int r = 0; r < 8; ++r) {
                float xv = sX[(tr * 8 + r) * 32 + kk];
                acc[r][0] += xv * wv0;
                acc[r][1] += xv * wv1;
                acc[r][2] += xv * wv2;
                acc[r][3] += xv * wv3;
            }
        }
    }
#pragma unroll
    for (int r = 0; r < 8; ++r) {
        int gr = row0 + tr * 8 + r;
        if (gr < nRows) {
#pragma unroll
            for (int j = 0; j < 4; ++j)
                Y[(size_t)gr * 128 + tc + 32 * j] = acc[r][j];
        }
    }
}

// ---------------- self-loop init: agg = h * dinv^2 ----------------
__global__ void k_self(const float* __restrict__ h, const float* __restrict__ dinv,
                       float* __restrict__ agg, int n) {
    int idx = blockIdx.x * blockDim.x + threadIdx.x;
    if (idx < n * DIM) {
        int i = idx >> 7;
        float d = dinv[i];
        agg[idx] = h[idx] * d * d;
    }
}

// ---------------- edge scatter: agg[dst] += h[src] * dinv[src]*dinv[dst] ----------------
__global__ void k_edge(const int* __restrict__ src, const int* __restrict__ dst,
                       const float* __restrict__ h, const float* __restrict__ dinv,
                       float* __restrict__ agg, int nE) {
    int idx = blockIdx.x * blockDim.x + threadIdx.x;
    int e = idx >> 7;
    int c = idx & 127;
    if (e < nE) {
        int s = src[e], d = dst[e];
        float coef = dinv[s] * dinv[d];
        atomicAdd(&agg[(size_t)d * 128 + c], h[(size_t)s * 128 + c] * coef);
    }
}

// ---------------- bias + leaky relu (in place) ----------------
__global__ void k_bias_relu(float* __restrict__ agg, const float* __restrict__ b, int n) {
    int idx = blockIdx.x * blockDim.x + threadIdx.x;
    if (idx < n * DIM) {
        float v = agg[idx] + b[idx & 127];
        agg[idx] = v > 0.0f ? v : NEG_SLOPE * v;
    }
}

// ---------------- pooling ----------------
__global__ void k_count(const int* __restrict__ batch, float* __restrict__ counts, int n) {
    int i = blockIdx.x * blockDim.x + threadIdx.x;
    if (i < n) atomicAdd(&counts[batch[i]], 1.0f);
}

__global__ void k_pool(const float* __restrict__ h, const int* __restrict__ batch,
                       float* __restrict__ out, int n) {
    int idx = blockIdx.x * blockDim.x + threadIdx.x;
    if (idx < n * DIM) {
        int i = idx >> 7;
        atomicAdd(&out[(size_t)batch[i] * 128 + (idx & 127)], h[idx]);
    }
}

__global__ void k_div(float* __restrict__ out, const float* __restrict__ counts, int ng) {
    int idx = blockIdx.x * blockDim.x + threadIdx.x;
    if (idx < ng * DIM) out[idx] /= fmaxf(counts[idx >> 7], 1.0f);
}

extern "C" void kernel_launch(void* const* d_in, const int* in_sizes, int n_in,
                              void* d_out, int out_size, void* d_ws, size_t ws_size,
                              hipStream_t stream) {
    const float* X  = (const float*)d_in[0];
    const float* W1 = (const float*)d_in[1];
    const float* b1 = (const float*)d_in[2];
    const float* W2 = (const float*)d_in[3];
    const float* b2 = (const float*)d_in[4];
    const int*   ei = (const int*)d_in[5];
    const int*   batch = (const int*)d_in[6];
    float* out = (float*)d_out;

    const int NN = in_sizes[0] / DIM;     // 50000
    const int NE = in_sizes[5] / 2;       // 600000
    const int NG = out_size / DIM;        // 1000

    const int* src = ei;
    const int* dst = ei + NE;

    char* ws = (char*)d_ws;
    float* dinv   = (float*)ws;                          // NN floats
    float* counts = (float*)(ws + 256 * 1024);           // NG floats
    float* bufA   = (float*)(ws + 512 * 1024);           // NN*128 floats
    float* bufB   = (float*)(ws + 512 * 1024 + (size_t)26 * 1024 * 1024);

    hipMemsetAsync(dinv, 0, (size_t)NN * 4, stream);
    hipMemsetAsync(counts, 0, (size_t)NG * 4, stream);
    hipMemsetAsync(out, 0, (size_t)out_size * 4, stream);

    const int B = 256;
    // degree -> dinv
    k_deg<<<(NE + B - 1) / B, B, 0, stream>>>(dst, dinv, NE);
    k_dinv<<<(NN + B - 1) / B, B, 0, stream>>>(dinv, NN);

    int gemm_grid = (NN + 63) / 64;
    int nodeElems = NN * DIM;
    int nodeGrid = (nodeElems + B - 1) / B;
    int edgeGrid = ((NE * DIM) + B - 1) / B;   // 76.8M threads / 256

    // ---- layer 1 ----
    k_gemm<<<gemm_grid, B, 0, stream>>>(X, W1, bufA, NN);
    k_self<<<nodeGrid, B, 0, stream>>>(bufA, dinv, bufB, NN);
    k_edge<<<edgeGrid, B, 0, stream>>>(src, dst, bufA, dinv, bufB, NE);
    k_bias_relu<<<nodeGrid, B, 0, stream>>>(bufB, b1, NN);

    // ---- layer 2 ----
    k_gemm<<<gemm_grid, B, 0, stream>>>(bufB, W2, bufA, NN);
    k_self<<<nodeGrid, B, 0, stream>>>(bufA, dinv, bufB, NN);
    k_edge<<<edgeGrid, B, 0, stream>>>(src, dst, bufA, dinv, bufB, NE);
    k_bias_relu<<<nodeGrid, B, 0, stream>>>(bufB, b2, NN);

    // ---- global mean pool ----
    k_count<<<(NN + B - 1) / B, B, 0, stream>>>(batch, counts, NN);
    k_pool<<<nodeGrid, B, 0, stream>>>(bufB, batch, out, NN);
    k_div<<<((NG * DIM) + B - 1) / B, B, 0, stream>>>(out, counts, NG);
}

// Round 2
// 507.644 us; speedup vs baseline: 1.5886x; 1.5886x over previous
//
#include <hip/hip_runtime.h>

#define DIM 128
#define NEG_SLOPE 0.01f

// ---------------- integer degree count ----------------
__global__ void k_degi(const int* __restrict__ dst, int* __restrict__ cnt, int nE) {
    int i = blockIdx.x * blockDim.x + threadIdx.x;
    if (i < nE) atomicAdd(&cnt[dst[i]], 1);
}

// dinv[i] = rsqrt(cnt[i] + 1)
__global__ void k_dinv(const int* __restrict__ cnt, float* __restrict__ dinv, int n) {
    int i = blockIdx.x * blockDim.x + threadIdx.x;
    if (i < n) dinv[i] = rsqrtf((float)cnt[i] + 1.0f);
}

// ---------------- single-block exclusive scan (n <= 1024*CHUNK) ----------------
__global__ __launch_bounds__(1024) void k_scan(const int* __restrict__ cnt,
                                               int* __restrict__ off, int n) {
    __shared__ int part[1024];
    const int t = threadIdx.x;
    const int chunk = (n + 1023) / 1024;
    const int base = t * chunk;
    int sum = 0;
    for (int i = 0; i < chunk; ++i) {
        int idx = base + i;
        if (idx < n) sum += cnt[idx];
    }
    part[t] = sum;
    __syncthreads();
    // Hillis-Steele inclusive scan
    for (int s = 1; s < 1024; s <<= 1) {
        int v = (t >= s) ? part[t - s] : 0;
        __syncthreads();
        part[t] += v;
        __syncthreads();
    }
    int run = part[t] - sum;  // exclusive prefix
    for (int i = 0; i < chunk; ++i) {
        int idx = base + i;
        if (idx < n) {
            off[idx] = run;
            run += cnt[idx];
        }
    }
    if (t == 1023) off[n] = part[1023];
}

// ---------------- CSR fill: slot = row_off[dst] + atomic cursor ----------------
__global__ void k_fill(const int* __restrict__ src, const int* __restrict__ dst,
                       const int* __restrict__ row_off, int* __restrict__ cursor,
                       const float* __restrict__ dinv,
                       int* __restrict__ eSrc, float* __restrict__ eCoef, int nE) {
    int e = blockIdx.x * blockDim.x + threadIdx.x;
    if (e < nE) {
        int s = src[e], d = dst[e];
        int pos = atomicAdd(&cursor[d], 1);
        int slot = row_off[d] + pos;
        eSrc[slot] = s;
        eCoef[slot] = dinv[s] * dinv[d];
    }
}

// ---------------- GEMM: Y[n,128] = X[n,128] @ W[128,128] ----------------
__global__ __launch_bounds__(256) void k_gemm(const float* __restrict__ X,
                                              const float* __restrict__ W,
                                              float* __restrict__ Y, int nRows) {
    __shared__ float sW[32 * 128];  // 16 KB
    __shared__ float sX[64 * 32];   // 8 KB
    const int t = threadIdx.x;
    const int row0 = blockIdx.x * 64;
    const int tc = t & 31;
    const int tr = t >> 5;

    float acc[8][4];
#pragma unroll
    for (int r = 0; r < 8; ++r)
#pragma unroll
        for (int j = 0; j < 4; ++j) acc[r][j] = 0.0f;

    for (int kb = 0; kb < 4; ++kb) {
        __syncthreads();
        for (int i = t; i < 1024; i += 256)
            ((float4*)sW)[i] = ((const float4*)(W + kb * 32 * 128))[i];
        for (int i = t; i < 512; i += 256) {
            int r = i >> 3, c4 = i & 7;
            int gr = row0 + r;
            float4 v = make_float4(0.f, 0.f, 0.f, 0.f);
            if (gr < nRows) v = *(const float4*)&X[(size_t)gr * 128 + kb * 32 + c4 * 4];
            *(float4*)&sX[r * 32 + c4 * 4] = v;
        }
        __syncthreads();
#pragma unroll
        for (int kk = 0; kk < 32; ++kk) {
            float wv0 = sW[kk * 128 + tc];
            float wv1 = sW[kk * 128 + tc + 32];
            float wv2 = sW[kk * 128 + tc + 64];
            float wv3 = sW[kk * 128 + tc + 96];
#pragma unroll
            for (int r = 0; r < 8; ++r) {
                float xv = sX[(tr * 8 + r) * 32 + kk];
                acc[r][0] += xv * wv0;
                acc[r][1] += xv * wv1;
                acc[r][2] += xv * wv2;
                acc[r][3] += xv * wv3;
            }
        }
    }
#pragma unroll
    for (int r = 0; r < 8; ++r) {
        int gr = row0 + tr * 8 + r;
        if (gr < nRows) {
#pragma unroll
            for (int j = 0; j < 4; ++j)
                Y[(size_t)gr * 128 + tc + 32 * j] = acc[r][j];
        }
    }
}

// ---------------- fused gather + self-loop + bias + leaky-relu ----------------
// one block (128 threads) per node; thread c handles feature column c
__global__ __launch_bounds__(128) void k_gather(const float* __restrict__ h,
                                                const int* __restrict__ row_off,
                                                const int* __restrict__ eSrc,
                                                const float* __restrict__ eCoef,
                                                const float* __restrict__ dinv,
                                                const float* __restrict__ bias,
                                                float* __restrict__ out, int n) {
    int i = blockIdx.x;
    int c = threadIdx.x;
    int beg = row_off[i], end = row_off[i + 1];
    float d = dinv[i];
    float acc = h[(size_t)i * DIM + c] * d * d;
    for (int e = beg; e < end; ++e) {
        int s = eSrc[e];
        float cf = eCoef[e];
        acc += h[(size_t)s * DIM + c] * cf;
    }
    float v = acc + bias[c];
    out[(size_t)i * DIM + c] = v > 0.0f ? v : NEG_SLOPE * v;
}

// ---------------- per-graph node counts ----------------
__global__ void k_gcnt(const int* __restrict__ batch, int* __restrict__ gcnt, int n) {
    int i = blockIdx.x * blockDim.x + threadIdx.x;
    if (i < n) atomicAdd(&gcnt[batch[i]], 1);
}

// ---------------- segmented mean pool (batch is sorted) ----------------
__global__ __launch_bounds__(128) void k_pool(const float* __restrict__ h,
                                              const int* __restrict__ gOff,
                                              float* __restrict__ out, int nG) {
    int g = blockIdx.x;
    int c = threadIdx.x;
    int beg = gOff[g], end = gOff[g + 1];
    float acc = 0.0f;
    for (int r = beg; r < end; ++r) acc += h[(size_t)r * DIM + c];
    float cntf = (float)(end - beg);
    out[(size_t)g * DIM + c] = acc / fmaxf(cntf, 1.0f);
}

extern "C" void kernel_launch(void* const* d_in, const int* in_sizes, int n_in,
                              void* d_out, int out_size, void* d_ws, size_t ws_size,
                              hipStream_t stream) {
    const float* X  = (const float*)d_in[0];
    const float* W1 = (const float*)d_in[1];
    const float* b1 = (const float*)d_in[2];
    const float* W2 = (const float*)d_in[3];
    const float* b2 = (const float*)d_in[4];
    const int*   ei = (const int*)d_in[5];
    const int*   batch = (const int*)d_in[6];
    float* out = (float*)d_out;

    const int NN = in_sizes[0] / DIM;     // 50000
    const int NE = in_sizes[5] / 2;       // 600000
    const int NG = out_size / DIM;        // 1000

    const int* src = ei;
    const int* dst = ei + NE;

    char* ws = (char*)d_ws;
    size_t o = 0;
    auto alloc = [&](size_t bytes) {
        char* p = ws + o;
        o += (bytes + 1023) & ~(size_t)1023;
        return p;
    };
    int*   cnt     = (int*)alloc((size_t)NN * 4);
    int*   cursor  = (int*)alloc((size_t)NN * 4);
    int*   row_off = (int*)alloc((size_t)(NN + 1) * 4);
    float* dinv    = (float*)alloc((size_t)NN * 4);
    int*   gcnt    = (int*)alloc((size_t)NG * 4);
    int*   gOff    = (int*)alloc((size_t)(NG + 1) * 4);
    int*   eSrc    = (int*)alloc((size_t)NE * 4);
    float* eCoef   = (float*)alloc((size_t)NE * 4);
    float* bufA    = (float*)alloc((size_t)NN * DIM * 4);
    float* bufB    = (float*)alloc((size_t)NN * DIM * 4);

    hipMemsetAsync(cnt, 0, (size_t)NN * 4, stream);
    hipMemsetAsync(cursor, 0, (size_t)NN * 4, stream);
    hipMemsetAsync(gcnt, 0, (size_t)NG * 4, stream);

    const int B = 256;
    // ---- CSR build (shared by both layers) ----
    k_degi<<<(NE + B - 1) / B, B, 0, stream>>>(dst, cnt, NE);
    k_scan<<<1, 1024, 0, stream>>>(cnt, row_off, NN);
    k_dinv<<<(NN + B - 1) / B, B, 0, stream>>>(cnt, dinv, NN);
    k_fill<<<(NE + B - 1) / B, B, 0, stream>>>(src, dst, row_off, cursor, dinv,
                                               eSrc, eCoef, NE);
    // ---- graph offsets for pooling ----
    k_gcnt<<<(NN + B - 1) / B, B, 0, stream>>>(batch, gcnt, NN);
    k_scan<<<1, 1024, 0, stream>>>(gcnt, gOff, NG);

    int gemm_grid = (NN + 63) / 64;

    // ---- layer 1 ----
    k_gemm<<<gemm_grid, B, 0, stream>>>(X, W1, bufA, NN);
    k_gather<<<NN, 128, 0, stream>>>(bufA, row_off, eSrc, eCoef, dinv, b1, bufB, NN);

    // ---- layer 2 ----
    k_gemm<<<gemm_grid, B, 0, stream>>>(bufB, W2, bufA, NN);
    k_gather<<<NN, 128, 0, stream>>>(bufA, row_off, eSrc, eCoef, dinv, b2, bufB, NN);

    // ---- global mean pool ----
    k_pool<<<NG, 128, 0, stream>>>(bufB, gOff, out, NG);
}

// Round 3
// 423.359 us; speedup vs baseline: 1.9049x; 1.1991x over previous
//
#include <hip/hip_runtime.h>

#define DIM 128
#define NEG_SLOPE 0.01f

// ---------------- integer degree count ----------------
__global__ void k_degi(const int* __restrict__ dst, int* __restrict__ cnt, int nE) {
    int i = blockIdx.x * blockDim.x + threadIdx.x;
    if (i < nE) atomicAdd(&cnt[dst[i]], 1);
}

// dinv[i] = rsqrt(cnt[i] + 1)
__global__ void k_dinv(const int* __restrict__ cnt, float* __restrict__ dinv, int n) {
    int i = blockIdx.x * blockDim.x + threadIdx.x;
    if (i < n) dinv[i] = rsqrtf((float)cnt[i] + 1.0f);
}

// ---------------- 3-pass multi-block exclusive scan ----------------
// pass 1: per-block (256 elems) total
__global__ __launch_bounds__(256) void k_scan1(const int* __restrict__ cnt,
                                               int* __restrict__ bsum, int n) {
    __shared__ int sh[256];
    int t = threadIdx.x;
    int i = blockIdx.x * 256 + t;
    sh[t] = (i < n) ? cnt[i] : 0;
    __syncthreads();
#pragma unroll
    for (int s = 128; s > 0; s >>= 1) {
        if (t < s) sh[t] += sh[t + s];
        __syncthreads();
    }
    if (t == 0) bsum[blockIdx.x] = sh[0];
}

// pass 2: single-block exclusive scan of block sums (nb <= 1024), in place
__global__ __launch_bounds__(1024) void k_scan2(int* __restrict__ bsum, int nb) {
    __shared__ int sh[1024];
    int t = threadIdx.x;
    int v = (t < nb) ? bsum[t] : 0;
    sh[t] = v;
    __syncthreads();
    for (int s = 1; s < 1024; s <<= 1) {
        int u = (t >= s) ? sh[t - s] : 0;
        __syncthreads();
        sh[t] += u;
        __syncthreads();
    }
    if (t < nb) bsum[t] = sh[t] - v;  // exclusive
}

// pass 3: local exclusive scan + block offset; also writes off[n] = total
__global__ __launch_bounds__(256) void k_scan3(const int* __restrict__ cnt,
                                               const int* __restrict__ bsum,
                                               int* __restrict__ off, int n) {
    __shared__ int sh[256];
    int t = threadIdx.x;
    int i = blockIdx.x * 256 + t;
    int v = (i < n) ? cnt[i] : 0;
    sh[t] = v;
    __syncthreads();
    for (int s = 1; s < 256; s <<= 1) {
        int u = (t >= s) ? sh[t - s] : 0;
        __syncthreads();
        sh[t] += u;
        __syncthreads();
    }
    int incl = sh[t];
    int base = bsum[blockIdx.x];
    if (i < n) off[i] = base + incl - v;
    if (i == n - 1) off[n] = base + incl;
}

// ---------------- CSR fill: slot = row_off[dst] + atomic cursor ----------------
__global__ void k_fill(const int* __restrict__ src, const int* __restrict__ dst,
                       const int* __restrict__ row_off, int* __restrict__ cursor,
                       const float* __restrict__ dinv,
                       int* __restrict__ eSrc, float* __restrict__ eCoef, int nE) {
    int e = blockIdx.x * blockDim.x + threadIdx.x;
    if (e < nE) {
        int s = src[e], d = dst[e];
        int pos = atomicAdd(&cursor[d], 1);
        int slot = row_off[d] + pos;
        eSrc[slot] = s;
        eCoef[slot] = dinv[s] * dinv[d];
    }
}

// ---------------- GEMM: Y[n,128] = X[n,128] @ W[128,128] ----------------
__global__ __launch_bounds__(256) void k_gemm(const float* __restrict__ X,
                                              const float* __restrict__ W,
                                              float* __restrict__ Y, int nRows) {
    __shared__ float sW[32 * 128];  // 16 KB
    __shared__ float sX[64 * 32];   // 8 KB
    const int t = threadIdx.x;
    const int row0 = blockIdx.x * 64;
    const int tc = t & 31;
    const int tr = t >> 5;

    float acc[8][4];
#pragma unroll
    for (int r = 0; r < 8; ++r)
#pragma unroll
        for (int j = 0; j < 4; ++j) acc[r][j] = 0.0f;

    for (int kb = 0; kb < 4; ++kb) {
        __syncthreads();
        for (int i = t; i < 1024; i += 256)
            ((float4*)sW)[i] = ((const float4*)(W + kb * 32 * 128))[i];
        for (int i = t; i < 512; i += 256) {
            int r = i >> 3, c4 = i & 7;
            int gr = row0 + r;
            float4 v = make_float4(0.f, 0.f, 0.f, 0.f);
            if (gr < nRows) v = *(const float4*)&X[(size_t)gr * 128 + kb * 32 + c4 * 4];
            *(float4*)&sX[r * 32 + c4 * 4] = v;
        }
        __syncthreads();
#pragma unroll
        for (int kk = 0; kk < 32; ++kk) {
            float wv0 = sW[kk * 128 + tc];
            float wv1 = sW[kk * 128 + tc + 32];
            float wv2 = sW[kk * 128 + tc + 64];
            float wv3 = sW[kk * 128 + tc + 96];
#pragma unroll
            for (int r = 0; r < 8; ++r) {
                float xv = sX[(tr * 8 + r) * 32 + kk];
                acc[r][0] += xv * wv0;
                acc[r][1] += xv * wv1;
                acc[r][2] += xv * wv2;
                acc[r][3] += xv * wv3;
            }
        }
    }
#pragma unroll
    for (int r = 0; r < 8; ++r) {
        int gr = row0 + tr * 8 + r;
        if (gr < nRows) {
#pragma unroll
            for (int j = 0; j < 4; ++j)
                Y[(size_t)gr * 128 + tc + 32 * j] = acc[r][j];
        }
    }
}

// ---------------- fused gather + self-loop + bias + leaky-relu ----------------
// one block (128 threads) per node; thread c handles feature column c
__global__ __launch_bounds__(128) void k_gather(const float* __restrict__ h,
                                                const int* __restrict__ row_off,
                                                const int* __restrict__ eSrc,
                                                const float* __restrict__ eCoef,
                                                const float* __restrict__ dinv,
                                                const float* __restrict__ bias,
                                                float* __restrict__ out, int n) {
    int i = blockIdx.x;
    int c = threadIdx.x;
    int beg = row_off[i], end = row_off[i + 1];
    float d = dinv[i];
    float acc = h[(size_t)i * DIM + c] * d * d;
    for (int e = beg; e < end; ++e) {
        int s = eSrc[e];
        float cf = eCoef[e];
        acc += h[(size_t)s * DIM + c] * cf;
    }
    float v = acc + bias[c];
    out[(size_t)i * DIM + c] = v > 0.0f ? v : NEG_SLOPE * v;
}

// ---------------- per-graph node counts ----------------
__global__ void k_gcnt(const int* __restrict__ batch, int* __restrict__ gcnt, int n) {
    int i = blockIdx.x * blockDim.x + threadIdx.x;
    if (i < n) atomicAdd(&gcnt[batch[i]], 1);
}

// ---------------- segmented mean pool (batch is sorted) ----------------
__global__ __launch_bounds__(128) void k_pool(const float* __restrict__ h,
                                              const int* __restrict__ gOff,
                                              float* __restrict__ out, int nG) {
    int g = blockIdx.x;
    int c = threadIdx.x;
    int beg = gOff[g], end = gOff[g + 1];
    float acc = 0.0f;
    for (int r = beg; r < end; ++r) acc += h[(size_t)r * DIM + c];
    float cntf = (float)(end - beg);
    out[(size_t)g * DIM + c] = acc / fmaxf(cntf, 1.0f);
}

static inline void run_scan(const int* cnt, int* bsum, int* off, int n,
                            hipStream_t stream) {
    int nb = (n + 255) / 256;
    k_scan1<<<nb, 256, 0, stream>>>(cnt, bsum, n);
    k_scan2<<<1, 1024, 0, stream>>>(bsum, nb);
    k_scan3<<<nb, 256, 0, stream>>>(cnt, bsum, off, n);
}

extern "C" void kernel_launch(void* const* d_in, const int* in_sizes, int n_in,
                              void* d_out, int out_size, void* d_ws, size_t ws_size,
                              hipStream_t stream) {
    const float* X  = (const float*)d_in[0];
    const float* W1 = (const float*)d_in[1];
    const float* b1 = (const float*)d_in[2];
    const float* W2 = (const float*)d_in[3];
    const float* b2 = (const float*)d_in[4];
    const int*   ei = (const int*)d_in[5];
    const int*   batch = (const int*)d_in[6];
    float* out = (float*)d_out;

    const int NN = in_sizes[0] / DIM;     // 50000
    const int NE = in_sizes[5] / 2;       // 600000
    const int NG = out_size / DIM;        // 1000

    const int* src = ei;
    const int* dst = ei + NE;

    char* ws = (char*)d_ws;
    size_t o = 0;
    auto alloc = [&](size_t bytes) {
        char* p = ws + o;
        o += (bytes + 1023) & ~(size_t)1023;
        return p;
    };
    int*   cnt     = (int*)alloc((size_t)NN * 4);
    int*   cursor  = (int*)alloc((size_t)NN * 4);
    int*   row_off = (int*)alloc((size_t)(NN + 1) * 4);
    float* dinv    = (float*)alloc((size_t)NN * 4);
    int*   bsum    = (int*)alloc((size_t)1024 * 4);
    int*   gcnt    = (int*)alloc((size_t)NG * 4);
    int*   gOff    = (int*)alloc((size_t)(NG + 1) * 4);
    int*   eSrc    = (int*)alloc((size_t)NE * 4);
    float* eCoef   = (float*)alloc((size_t)NE * 4);
    float* bufA    = (float*)alloc((size_t)NN * DIM * 4);
    float* bufB    = (float*)alloc((size_t)NN * DIM * 4);

    hipMemsetAsync(cnt, 0, (size_t)NN * 4, stream);
    hipMemsetAsync(cursor, 0, (size_t)NN * 4, stream);
    hipMemsetAsync(gcnt, 0, (size_t)NG * 4, stream);

    const int B = 256;
    // ---- CSR build (shared by both layers) ----
    k_degi<<<(NE + B - 1) / B, B, 0, stream>>>(dst, cnt, NE);
    run_scan(cnt, bsum, row_off, NN, stream);
    k_dinv<<<(NN + B - 1) / B, B, 0, stream>>>(cnt, dinv, NN);
    k_fill<<<(NE + B - 1) / B, B, 0, stream>>>(src, dst, row_off, cursor, dinv,
                                               eSrc, eCoef, NE);
    // ---- graph offsets for pooling ----
    k_gcnt<<<(NN + B - 1) / B, B, 0, stream>>>(batch, gcnt, NN);
    run_scan(gcnt, bsum, gOff, NG, stream);

    int gemm_grid = (NN + 63) / 64;

    // ---- layer 1 ----
    k_gemm<<<gemm_grid, B, 0, stream>>>(X, W1, bufA, NN);
    k_gather<<<NN, 128, 0, stream>>>(bufA, row_off, eSrc, eCoef, dinv, b1, bufB, NN);

    // ---- layer 2 ----
    k_gemm<<<gemm_grid, B, 0, stream>>>(bufB, W2, bufA, NN);
    k_gather<<<NN, 128, 0, stream>>>(bufA, row_off, eSrc, eCoef, dinv, b2, bufB, NN);

    // ---- global mean pool ----
    k_pool<<<NG, 128, 0, stream>>>(bufB, gOff, out, NG);
}

// Round 4
// 363.948 us; speedup vs baseline: 2.2159x; 1.1632x over previous
//
#include <hip/hip_runtime.h>

#define DIM 128
#define NEG_SLOPE 0.01f

// ---------------- integer degree count ----------------
__global__ void k_degi(const int* __restrict__ dst, int* __restrict__ cnt, int nE) {
    int i = blockIdx.x * blockDim.x + threadIdx.x;
    if (i < nE) atomicAdd(&cnt[dst[i]], 1);
}

// dinv[i] = rsqrt(cnt[i] + 1)
__global__ void k_dinv(const int* __restrict__ cnt, float* __restrict__ dinv, int n) {
    int i = blockIdx.x * blockDim.x + threadIdx.x;
    if (i < n) dinv[i] = rsqrtf((float)cnt[i] + 1.0f);
}

// ---------------- 3-pass multi-block exclusive scan ----------------
__global__ __launch_bounds__(256) void k_scan1(const int* __restrict__ cnt,
                                               int* __restrict__ bsum, int n) {
    __shared__ int sh[256];
    int t = threadIdx.x;
    int i = blockIdx.x * 256 + t;
    sh[t] = (i < n) ? cnt[i] : 0;
    __syncthreads();
#pragma unroll
    for (int s = 128; s > 0; s >>= 1) {
        if (t < s) sh[t] += sh[t + s];
        __syncthreads();
    }
    if (t == 0) bsum[blockIdx.x] = sh[0];
}

__global__ __launch_bounds__(1024) void k_scan2(int* __restrict__ bsum, int nb) {
    __shared__ int sh[1024];
    int t = threadIdx.x;
    int v = (t < nb) ? bsum[t] : 0;
    sh[t] = v;
    __syncthreads();
    for (int s = 1; s < 1024; s <<= 1) {
        int u = (t >= s) ? sh[t - s] : 0;
        __syncthreads();
        sh[t] += u;
        __syncthreads();
    }
    if (t < nb) bsum[t] = sh[t] - v;  // exclusive
}

__global__ __launch_bounds__(256) void k_scan3(const int* __restrict__ cnt,
                                               const int* __restrict__ bsum,
                                               int* __restrict__ off, int n) {
    __shared__ int sh[256];
    int t = threadIdx.x;
    int i = blockIdx.x * 256 + t;
    int v = (i < n) ? cnt[i] : 0;
    sh[t] = v;
    __syncthreads();
    for (int s = 1; s < 256; s <<= 1) {
        int u = (t >= s) ? sh[t - s] : 0;
        __syncthreads();
        sh[t] += u;
        __syncthreads();
    }
    int incl = sh[t];
    int base = bsum[blockIdx.x];
    if (i < n) off[i] = base + incl - v;
    if (i == n - 1) off[n] = base + incl;
}

// ---------------- CSR fill: slot = row_off[dst] + atomic cursor ----------------
// packs (src, coef) into int2
__global__ void k_fill(const int* __restrict__ src, const int* __restrict__ dst,
                       const int* __restrict__ row_off, int* __restrict__ cursor,
                       const float* __restrict__ dinv,
                       int2* __restrict__ eData, int nE) {
    int e = blockIdx.x * blockDim.x + threadIdx.x;
    if (e < nE) {
        int s = src[e], d = dst[e];
        int pos = atomicAdd(&cursor[d], 1);
        int slot = row_off[d] + pos;
        float coef = dinv[s] * dinv[d];
        eData[slot] = make_int2(s, __float_as_int(coef));
    }
}

// ---------------- GEMM: Y[n,128] = X[n,128] @ W[128,128] ----------------
__global__ __launch_bounds__(256) void k_gemm(const float* __restrict__ X,
                                              const float* __restrict__ W,
                                              float* __restrict__ Y, int nRows) {
    __shared__ float sW[32 * 128];  // 16 KB
    __shared__ float sX[64 * 32];   // 8 KB
    const int t = threadIdx.x;
    const int row0 = blockIdx.x * 64;
    const int tc = t & 31;
    const int tr = t >> 5;

    float acc[8][4];
#pragma unroll
    for (int r = 0; r < 8; ++r)
#pragma unroll
        for (int j = 0; j < 4; ++j) acc[r][j] = 0.0f;

    for (int kb = 0; kb < 4; ++kb) {
        __syncthreads();
        for (int i = t; i < 1024; i += 256)
            ((float4*)sW)[i] = ((const float4*)(W + kb * 32 * 128))[i];
        for (int i = t; i < 512; i += 256) {
            int r = i >> 3, c4 = i & 7;
            int gr = row0 + r;
            float4 v = make_float4(0.f, 0.f, 0.f, 0.f);
            if (gr < nRows) v = *(const float4*)&X[(size_t)gr * 128 + kb * 32 + c4 * 4];
            *(float4*)&sX[r * 32 + c4 * 4] = v;
        }
        __syncthreads();
#pragma unroll
        for (int kk = 0; kk < 32; ++kk) {
            float wv0 = sW[kk * 128 + tc];
            float wv1 = sW[kk * 128 + tc + 32];
            float wv2 = sW[kk * 128 + tc + 64];
            float wv3 = sW[kk * 128 + tc + 96];
#pragma unroll
            for (int r = 0; r < 8; ++r) {
                float xv = sX[(tr * 8 + r) * 32 + kk];
                acc[r][0] += xv * wv0;
                acc[r][1] += xv * wv1;
                acc[r][2] += xv * wv2;
                acc[r][3] += xv * wv3;
            }
        }
    }
#pragma unroll
    for (int r = 0; r < 8; ++r) {
        int gr = row0 + tr * 8 + r;
        if (gr < nRows) {
#pragma unroll
            for (int j = 0; j < 4; ++j)
                Y[(size_t)gr * 128 + tc + 32 * j] = acc[r][j];
        }
    }
}

// ---------------- fused gather + self-loop + bias + leaky-relu ----------------
// 32 lanes per node (float4/lane), 256-thread block = 8 nodes, 4-way unroll
__global__ __launch_bounds__(256) void k_gather(const float4* __restrict__ h4,
                                                const int* __restrict__ row_off,
                                                const int2* __restrict__ eData,
                                                const float* __restrict__ dinv,
                                                const float4* __restrict__ bias4,
                                                float4* __restrict__ out4, int n) {
    const int g = threadIdx.x >> 5;       // node group 0..7
    const int l = threadIdx.x & 31;       // lane within group: 4 cols
    const int i = blockIdx.x * 8 + g;
    if (i >= n) return;
    const int beg = row_off[i], end = row_off[i + 1];
    const float d = dinv[i];
    const float dd = d * d;
    float4 hv = h4[(size_t)i * 32 + l];
    float4 acc;
    acc.x = hv.x * dd; acc.y = hv.y * dd; acc.z = hv.z * dd; acc.w = hv.w * dd;

    int e = beg;
    for (; e + 4 <= end; e += 4) {
        int2 m0 = eData[e];
        int2 m1 = eData[e + 1];
        int2 m2 = eData[e + 2];
        int2 m3 = eData[e + 3];
        float4 v0 = h4[(size_t)m0.x * 32 + l];
        float4 v1 = h4[(size_t)m1.x * 32 + l];
        float4 v2 = h4[(size_t)m2.x * 32 + l];
        float4 v3 = h4[(size_t)m3.x * 32 + l];
        float c0 = __int_as_float(m0.y);
        float c1 = __int_as_float(m1.y);
        float c2 = __int_as_float(m2.y);
        float c3 = __int_as_float(m3.y);
        acc.x += v0.x * c0 + v1.x * c1 + v2.x * c2 + v3.x * c3;
        acc.y += v0.y * c0 + v1.y * c1 + v2.y * c2 + v3.y * c3;
        acc.z += v0.z * c0 + v1.z * c1 + v2.z * c2 + v3.z * c3;
        acc.w += v0.w * c0 + v1.w * c1 + v2.w * c2 + v3.w * c3;
    }
    for (; e < end; ++e) {
        int2 m = eData[e];
        float4 v = h4[(size_t)m.x * 32 + l];
        float c = __int_as_float(m.y);
        acc.x += v.x * c;
        acc.y += v.y * c;
        acc.z += v.z * c;
        acc.w += v.w * c;
    }
    float4 b = bias4[l];
    float4 r;
    r.x = acc.x + b.x; r.x = r.x > 0.f ? r.x : NEG_SLOPE * r.x;
    r.y = acc.y + b.y; r.y = r.y > 0.f ? r.y : NEG_SLOPE * r.y;
    r.z = acc.z + b.z; r.z = r.z > 0.f ? r.z : NEG_SLOPE * r.z;
    r.w = acc.w + b.w; r.w = r.w > 0.f ? r.w : NEG_SLOPE * r.w;
    out4[(size_t)i * 32 + l] = r;
}

// ---------------- per-graph node counts ----------------
__global__ void k_gcnt(const int* __restrict__ batch, int* __restrict__ gcnt, int n) {
    int i = blockIdx.x * blockDim.x + threadIdx.x;
    if (i < n) atomicAdd(&gcnt[batch[i]], 1);
}

// ---------------- segmented mean pool (batch is sorted) ----------------
__global__ __launch_bounds__(128) void k_pool(const float* __restrict__ h,
                                              const int* __restrict__ gOff,
                                              float* __restrict__ out, int nG) {
    int g = blockIdx.x;
    int c = threadIdx.x;
    int beg = gOff[g], end = gOff[g + 1];
    float acc = 0.0f;
    for (int r = beg; r < end; ++r) acc += h[(size_t)r * DIM + c];
    float cntf = (float)(end - beg);
    out[(size_t)g * DIM + c] = acc / fmaxf(cntf, 1.0f);
}

static inline void run_scan(const int* cnt, int* bsum, int* off, int n,
                            hipStream_t stream) {
    int nb = (n + 255) / 256;
    k_scan1<<<nb, 256, 0, stream>>>(cnt, bsum, n);
    k_scan2<<<1, 1024, 0, stream>>>(bsum, nb);
    k_scan3<<<nb, 256, 0, stream>>>(cnt, bsum, off, n);
}

extern "C" void kernel_launch(void* const* d_in, const int* in_sizes, int n_in,
                              void* d_out, int out_size, void* d_ws, size_t ws_size,
                              hipStream_t stream) {
    const float* X  = (const float*)d_in[0];
    const float* W1 = (const float*)d_in[1];
    const float* b1 = (const float*)d_in[2];
    const float* W2 = (const float*)d_in[3];
    const float* b2 = (const float*)d_in[4];
    const int*   ei = (const int*)d_in[5];
    const int*   batch = (const int*)d_in[6];
    float* out = (float*)d_out;

    const int NN = in_sizes[0] / DIM;     // 50000
    const int NE = in_sizes[5] / 2;       // 600000
    const int NG = out_size / DIM;        // 1000

    const int* src = ei;
    const int* dst = ei + NE;

    char* ws = (char*)d_ws;
    size_t o = 0;
    auto alloc = [&](size_t bytes) {
        char* p = ws + o;
        o += (bytes + 1023) & ~(size_t)1023;
        return p;
    };
    int*   cnt     = (int*)alloc((size_t)NN * 4);
    int*   cursor  = (int*)alloc((size_t)NN * 4);
    int*   row_off = (int*)alloc((size_t)(NN + 1) * 4);
    float* dinv    = (float*)alloc((size_t)NN * 4);
    int*   bsum    = (int*)alloc((size_t)1024 * 4);
    int*   gcnt    = (int*)alloc((size_t)NG * 4);
    int*   gOff    = (int*)alloc((size_t)(NG + 1) * 4);
    int2*  eData   = (int2*)alloc((size_t)NE * 8);
    float* bufA    = (float*)alloc((size_t)NN * DIM * 4);
    float* bufB    = (float*)alloc((size_t)NN * DIM * 4);

    hipMemsetAsync(cnt, 0, (size_t)NN * 4, stream);
    hipMemsetAsync(cursor, 0, (size_t)NN * 4, stream);
    hipMemsetAsync(gcnt, 0, (size_t)NG * 4, stream);

    const int B = 256;
    // ---- CSR build (shared by both layers) ----
    k_degi<<<(NE + B - 1) / B, B, 0, stream>>>(dst, cnt, NE);
    run_scan(cnt, bsum, row_off, NN, stream);
    k_dinv<<<(NN + B - 1) / B, B, 0, stream>>>(cnt, dinv, NN);
    k_fill<<<(NE + B - 1) / B, B, 0, stream>>>(src, dst, row_off, cursor, dinv,
                                               eData, NE);
    // ---- graph offsets for pooling ----
    k_gcnt<<<(NN + B - 1) / B, B, 0, stream>>>(batch, gcnt, NN);
    run_scan(gcnt, bsum, gOff, NG, stream);

    int gemm_grid = (NN + 63) / 64;
    int gather_grid = (NN + 7) / 8;

    // ---- layer 1 ----
    k_gemm<<<gemm_grid, B, 0, stream>>>(X, W1, bufA, NN);
    k_gather<<<gather_grid, B, 0, stream>>>((const float4*)bufA, row_off, eData,
                                            dinv, (const float4*)b1,
                                            (float4*)bufB, NN);

    // ---- layer 2 ----
    k_gemm<<<gemm_grid, B, 0, stream>>>(bufB, W2, bufA, NN);
    k_gather<<<gather_grid, B, 0, stream>>>((const float4*)bufA, row_off, eData,
                                            dinv, (const float4*)b2,
                                            (float4*)bufB, NN);

    // ---- global mean pool ----
    k_pool<<<NG, 128, 0, stream>>>(bufB, gOff, out, NG);
}

// Round 5
// 343.189 us; speedup vs baseline: 2.3499x; 1.0605x over previous
//
#include <hip/hip_runtime.h>

#define DIM 128
#define NEG_SLOPE 0.01f

// ---------------- integer degree count ----------------
__global__ void k_degi(const int* __restrict__ dst, int* __restrict__ cnt, int nE) {
    int i = blockIdx.x * blockDim.x + threadIdx.x;
    if (i < nE) atomicAdd(&cnt[dst[i]], 1);
}

// dinv[i] = rsqrt(cnt[i] + 1)
__global__ void k_dinv(const int* __restrict__ cnt, float* __restrict__ dinv, int n) {
    int i = blockIdx.x * blockDim.x + threadIdx.x;
    if (i < n) dinv[i] = rsqrtf((float)cnt[i] + 1.0f);
}

// ---------------- 3-pass multi-block exclusive scan ----------------
__global__ __launch_bounds__(256) void k_scan1(const int* __restrict__ cnt,
                                               int* __restrict__ bsum, int n) {
    __shared__ int sh[256];
    int t = threadIdx.x;
    int i = blockIdx.x * 256 + t;
    sh[t] = (i < n) ? cnt[i] : 0;
    __syncthreads();
#pragma unroll
    for (int s = 128; s > 0; s >>= 1) {
        if (t < s) sh[t] += sh[t + s];
        __syncthreads();
    }
    if (t == 0) bsum[blockIdx.x] = sh[0];
}

__global__ __launch_bounds__(1024) void k_scan2(int* __restrict__ bsum, int nb) {
    __shared__ int sh[1024];
    int t = threadIdx.x;
    int v = (t < nb) ? bsum[t] : 0;
    sh[t] = v;
    __syncthreads();
    for (int s = 1; s < 1024; s <<= 1) {
        int u = (t >= s) ? sh[t - s] : 0;
        __syncthreads();
        sh[t] += u;
        __syncthreads();
    }
    if (t < nb) bsum[t] = sh[t] - v;  // exclusive
}

__global__ __launch_bounds__(256) void k_scan3(const int* __restrict__ cnt,
                                               const int* __restrict__ bsum,
                                               int* __restrict__ off, int n) {
    __shared__ int sh[256];
    int t = threadIdx.x;
    int i = blockIdx.x * 256 + t;
    int v = (i < n) ? cnt[i] : 0;
    sh[t] = v;
    __syncthreads();
    for (int s = 1; s < 256; s <<= 1) {
        int u = (t >= s) ? sh[t - s] : 0;
        __syncthreads();
        sh[t] += u;
        __syncthreads();
    }
    int incl = sh[t];
    int base = bsum[blockIdx.x];
    if (i < n) off[i] = base + incl - v;
    if (i == n - 1) off[n] = base + incl;
}

// ---------------- CSR fill: slot = row_off[dst] + atomic cursor ----------------
__global__ void k_fill(const int* __restrict__ src, const int* __restrict__ dst,
                       const int* __restrict__ row_off, int* __restrict__ cursor,
                       const float* __restrict__ dinv,
                       int2* __restrict__ eData, int nE) {
    int e = blockIdx.x * blockDim.x + threadIdx.x;
    if (e < nE) {
        int s = src[e], d = dst[e];
        int pos = atomicAdd(&cursor[d], 1);
        int slot = row_off[d] + pos;
        float coef = dinv[s] * dinv[d];
        eData[slot] = make_int2(s, __float_as_int(coef));
    }
}

// ---------------- GEMM: Y[n,128] = X[n,128] @ W[128,128] ----------------
// Block 256 threads, tile 64 rows x 128 cols, K-slab 32.
// Thread tile: 4 rows (tr*4..), 8 cols {c0..c0+3, c0+64..c0+67}, c0=(t&15)*4.
// All LDS reads are b128: X staged transposed, W cols split at +64 for 2-way-free banks.
__global__ __launch_bounds__(256) void k_gemm(const float* __restrict__ X,
                                              const float* __restrict__ W,
                                              float* __restrict__ Y, int nRows) {
    __shared__ float sW[32][128];   // 16 KB
    __shared__ float sXt[32][64];   // 8 KB, [k][row]
    const int t = threadIdx.x;
    const int row0 = blockIdx.x * 64;
    const int c0 = (t & 15) * 4;
    const int tr = (t >> 4) * 4;

    float acc[4][8];
#pragma unroll
    for (int r = 0; r < 4; ++r)
#pragma unroll
        for (int c = 0; c < 8; ++c) acc[r][c] = 0.0f;

    for (int kb = 0; kb < 4; ++kb) {
        __syncthreads();
        // stage W slab [32][128]: 1024 float4, 4 per thread
#pragma unroll
        for (int rep = 0; rep < 4; ++rep) {
            int i = t + rep * 256;
            int k = i >> 5, c4 = (i & 31) * 4;
            *(float4*)&sW[k][c4] = *(const float4*)&W[(size_t)(kb * 32 + k) * 128 + c4];
        }
        // stage X^T slab [32][64]: 512 float4 reads, scalar transposed writes
#pragma unroll
        for (int rep = 0; rep < 2; ++rep) {
            int i = t + rep * 256;
            int r = i & 63, k4 = (i >> 6) * 4;
            int gr = row0 + r;
            float4 v = make_float4(0.f, 0.f, 0.f, 0.f);
            if (gr < nRows) v = *(const float4*)&X[(size_t)gr * 128 + kb * 32 + k4];
            sXt[k4 + 0][r] = v.x;
            sXt[k4 + 1][r] = v.y;
            sXt[k4 + 2][r] = v.z;
            sXt[k4 + 3][r] = v.w;
        }
        __syncthreads();
#pragma unroll
        for (int k = 0; k < 32; ++k) {
            float4 xv = *(float4*)&sXt[k][tr];
            float4 w0 = *(float4*)&sW[k][c0];
            float4 w1 = *(float4*)&sW[k][c0 + 64];
            float xr[4] = {xv.x, xv.y, xv.z, xv.w};
            float wc[8] = {w0.x, w0.y, w0.z, w0.w, w1.x, w1.y, w1.z, w1.w};
#pragma unroll
            for (int r = 0; r < 4; ++r)
#pragma unroll
                for (int c = 0; c < 8; ++c) acc[r][c] += xr[r] * wc[c];
        }
    }
#pragma unroll
    for (int r = 0; r < 4; ++r) {
        int gr = row0 + tr + r;
        if (gr < nRows) {
            float4 o0 = make_float4(acc[r][0], acc[r][1], acc[r][2], acc[r][3]);
            float4 o1 = make_float4(acc[r][4], acc[r][5], acc[r][6], acc[r][7]);
            *(float4*)&Y[(size_t)gr * 128 + c0] = o0;
            *(float4*)&Y[(size_t)gr * 128 + c0 + 64] = o1;
        }
    }
}

// ---------------- fused gather + self-loop + bias + leaky-relu ----------------
// 32 lanes per node (float4/lane), 256-thread block = 8 nodes, 4-way unroll
__global__ __launch_bounds__(256) void k_gather(const float4* __restrict__ h4,
                                                const int* __restrict__ row_off,
                                                const int2* __restrict__ eData,
                                                const float* __restrict__ dinv,
                                                const float4* __restrict__ bias4,
                                                float4* __restrict__ out4, int n) {
    const int g = threadIdx.x >> 5;
    const int l = threadIdx.x & 31;
    const int i = blockIdx.x * 8 + g;
    if (i >= n) return;
    const int beg = row_off[i], end = row_off[i + 1];
    const float d = dinv[i];
    const float dd = d * d;
    float4 hv = h4[(size_t)i * 32 + l];
    float4 acc;
    acc.x = hv.x * dd; acc.y = hv.y * dd; acc.z = hv.z * dd; acc.w = hv.w * dd;

    int e = beg;
    for (; e + 4 <= end; e += 4) {
        int2 m0 = eData[e];
        int2 m1 = eData[e + 1];
        int2 m2 = eData[e + 2];
        int2 m3 = eData[e + 3];
        float4 v0 = h4[(size_t)m0.x * 32 + l];
        float4 v1 = h4[(size_t)m1.x * 32 + l];
        float4 v2 = h4[(size_t)m2.x * 32 + l];
        float4 v3 = h4[(size_t)m3.x * 32 + l];
        float c0 = __int_as_float(m0.y);
        float c1 = __int_as_float(m1.y);
        float c2 = __int_as_float(m2.y);
        float c3 = __int_as_float(m3.y);
        acc.x += v0.x * c0 + v1.x * c1 + v2.x * c2 + v3.x * c3;
        acc.y += v0.y * c0 + v1.y * c1 + v2.y * c2 + v3.y * c3;
        acc.z += v0.z * c0 + v1.z * c1 + v2.z * c2 + v3.z * c3;
        acc.w += v0.w * c0 + v1.w * c1 + v2.w * c2 + v3.w * c3;
    }
    for (; e < end; ++e) {
        int2 m = eData[e];
        float4 v = h4[(size_t)m.x * 32 + l];
        float c = __int_as_float(m.y);
        acc.x += v.x * c;
        acc.y += v.y * c;
        acc.z += v.z * c;
        acc.w += v.w * c;
    }
    float4 b = bias4[l];
    float4 r;
    r.x = acc.x + b.x; r.x = r.x > 0.f ? r.x : NEG_SLOPE * r.x;
    r.y = acc.y + b.y; r.y = r.y > 0.f ? r.y : NEG_SLOPE * r.y;
    r.z = acc.z + b.z; r.z = r.z > 0.f ? r.z : NEG_SLOPE * r.z;
    r.w = acc.w + b.w; r.w = r.w > 0.f ? r.w : NEG_SLOPE * r.w;
    out4[(size_t)i * 32 + l] = r;
}

// ---------------- per-graph node counts ----------------
__global__ void k_gcnt(const int* __restrict__ batch, int* __restrict__ gcnt, int n) {
    int i = blockIdx.x * blockDim.x + threadIdx.x;
    if (i < n) atomicAdd(&gcnt[batch[i]], 1);
}

// ---------------- segmented mean pool (batch is sorted) ----------------
__global__ __launch_bounds__(128) void k_pool(const float* __restrict__ h,
                                              const int* __restrict__ gOff,
                                              float* __restrict__ out, int nG) {
    int g = blockIdx.x;
    int c = threadIdx.x;
    int beg = gOff[g], end = gOff[g + 1];
    float acc = 0.0f;
    for (int r = beg; r < end; ++r) acc += h[(size_t)r * DIM + c];
    float cntf = (float)(end - beg);
    out[(size_t)g * DIM + c] = acc / fmaxf(cntf, 1.0f);
}

static inline void run_scan(const int* cnt, int* bsum, int* off, int n,
                            hipStream_t stream) {
    int nb = (n + 255) / 256;
    k_scan1<<<nb, 256, 0, stream>>>(cnt, bsum, n);
    k_scan2<<<1, 1024, 0, stream>>>(bsum, nb);
    k_scan3<<<nb, 256, 0, stream>>>(cnt, bsum, off, n);
}

extern "C" void kernel_launch(void* const* d_in, const int* in_sizes, int n_in,
                              void* d_out, int out_size, void* d_ws, size_t ws_size,
                              hipStream_t stream) {
    const float* X  = (const float*)d_in[0];
    const float* W1 = (const float*)d_in[1];
    const float* b1 = (const float*)d_in[2];
    const float* W2 = (const float*)d_in[3];
    const float* b2 = (const float*)d_in[4];
    const int*   ei = (const int*)d_in[5];
    const int*   batch = (const int*)d_in[6];
    float* out = (float*)d_out;

    const int NN = in_sizes[0] / DIM;     // 50000
    const int NE = in_sizes[5] / 2;       // 600000
    const int NG = out_size / DIM;        // 1000

    const int* src = ei;
    const int* dst = ei + NE;

    char* ws = (char*)d_ws;
    size_t o = 0;
    auto alloc = [&](size_t bytes) {
        char* p = ws + o;
        o += (bytes + 1023) & ~(size_t)1023;
        return p;
    };
    int*   cnt     = (int*)alloc((size_t)NN * 4);
    int*   cursor  = (int*)alloc((size_t)NN * 4);
    int*   row_off = (int*)alloc((size_t)(NN + 1) * 4);
    float* dinv    = (float*)alloc((size_t)NN * 4);
    int*   bsum    = (int*)alloc((size_t)1024 * 4);
    int*   gcnt    = (int*)alloc((size_t)NG * 4);
    int*   gOff    = (int*)alloc((size_t)(NG + 1) * 4);
    int2*  eData   = (int2*)alloc((size_t)NE * 8);
    float* bufA    = (float*)alloc((size_t)NN * DIM * 4);
    float* bufB    = (float*)alloc((size_t)NN * DIM * 4);

    hipMemsetAsync(cnt, 0, (size_t)NN * 4, stream);
    hipMemsetAsync(cursor, 0, (size_t)NN * 4, stream);
    hipMemsetAsync(gcnt, 0, (size_t)NG * 4, stream);

    const int B = 256;
    // ---- CSR build (shared by both layers) ----
    k_degi<<<(NE + B - 1) / B, B, 0, stream>>>(dst, cnt, NE);
    run_scan(cnt, bsum, row_off, NN, stream);
    k_dinv<<<(NN + B - 1) / B, B, 0, stream>>>(cnt, dinv, NN);
    k_fill<<<(NE + B - 1) / B, B, 0, stream>>>(src, dst, row_off, cursor, dinv,
                                               eData, NE);
    // ---- graph offsets for pooling ----
    k_gcnt<<<(NN + B - 1) / B, B, 0, stream>>>(batch, gcnt, NN);
    run_scan(gcnt, bsum, gOff, NG, stream);

    int gemm_grid = (NN + 63) / 64;
    int gather_grid = (NN + 7) / 8;

    // ---- layer 1 ----
    k_gemm<<<gemm_grid, B, 0, stream>>>(X, W1, bufA, NN);
    k_gather<<<gather_grid, B, 0, stream>>>((const float4*)bufA, row_off, eData,
                                            dinv, (const float4*)b1,
                                            (float4*)bufB, NN);

    // ---- layer 2 ----
    k_gemm<<<gemm_grid, B, 0, stream>>>(bufB, W2, bufA, NN);
    k_gather<<<gather_grid, B, 0, stream>>>((const float4*)bufA, row_off, eData,
                                            dinv, (const float4*)b2,
                                            (float4*)bufB, NN);

    // ---- global mean pool ----
    k_pool<<<NG, 128, 0, stream>>>(bufB, gOff, out, NG);
}

// Round 6
// 293.939 us; speedup vs baseline: 2.7436x; 1.1676x over previous
//
#include <hip/hip_runtime.h>

#define DIM 128
#define NEG_SLOPE 0.01f

typedef short short8 __attribute__((ext_vector_type(8)));
typedef float f32x4 __attribute__((ext_vector_type(4)));

// round-to-nearest-even f32 -> bf16 (as ushort)
__device__ __forceinline__ unsigned short f2bf(float f) {
    unsigned u = __float_as_uint(f);
    u = u + 0x7FFFu + ((u >> 16) & 1u);
    return (unsigned short)(u >> 16);
}
__device__ __forceinline__ float bf2f(unsigned short s) {
    return __uint_as_float((unsigned)s << 16);
}

// ---------------- integer degree count ----------------
__global__ void k_degi(const int* __restrict__ dst, int* __restrict__ cnt, int nE) {
    int i = blockIdx.x * blockDim.x + threadIdx.x;
    if (i < nE) atomicAdd(&cnt[dst[i]], 1);
}

__global__ void k_dinv(const int* __restrict__ cnt, float* __restrict__ dinv, int n) {
    int i = blockIdx.x * blockDim.x + threadIdx.x;
    if (i < n) dinv[i] = rsqrtf((float)cnt[i] + 1.0f);
}

// ---------------- 3-pass multi-block exclusive scan ----------------
__global__ __launch_bounds__(256) void k_scan1(const int* __restrict__ cnt,
                                               int* __restrict__ bsum, int n) {
    __shared__ int sh[256];
    int t = threadIdx.x;
    int i = blockIdx.x * 256 + t;
    sh[t] = (i < n) ? cnt[i] : 0;
    __syncthreads();
#pragma unroll
    for (int s = 128; s > 0; s >>= 1) {
        if (t < s) sh[t] += sh[t + s];
        __syncthreads();
    }
    if (t == 0) bsum[blockIdx.x] = sh[0];
}

__global__ __launch_bounds__(1024) void k_scan2(int* __restrict__ bsum, int nb) {
    __shared__ int sh[1024];
    int t = threadIdx.x;
    int v = (t < nb) ? bsum[t] : 0;
    sh[t] = v;
    __syncthreads();
    for (int s = 1; s < 1024; s <<= 1) {
        int u = (t >= s) ? sh[t - s] : 0;
        __syncthreads();
        sh[t] += u;
        __syncthreads();
    }
    if (t < nb) bsum[t] = sh[t] - v;  // exclusive
}

__global__ __launch_bounds__(256) void k_scan3(const int* __restrict__ cnt,
                                               const int* __restrict__ bsum,
                                               int* __restrict__ off, int n) {
    __shared__ int sh[256];
    int t = threadIdx.x;
    int i = blockIdx.x * 256 + t;
    int v = (i < n) ? cnt[i] : 0;
    sh[t] = v;
    __syncthreads();
    for (int s = 1; s < 256; s <<= 1) {
        int u = (t >= s) ? sh[t - s] : 0;
        __syncthreads();
        sh[t] += u;
        __syncthreads();
    }
    int incl = sh[t];
    int base = bsum[blockIdx.x];
    if (i < n) off[i] = base + incl - v;
    if (i == n - 1) off[n] = base + incl;
}

// ---------------- CSR fill ----------------
__global__ void k_fill(const int* __restrict__ src, const int* __restrict__ dst,
                       const int* __restrict__ row_off, int* __restrict__ cursor,
                       const float* __restrict__ dinv,
                       int2* __restrict__ eData, int nE) {
    int e = blockIdx.x * blockDim.x + threadIdx.x;
    if (e < nE) {
        int s = src[e], d = dst[e];
        int pos = atomicAdd(&cursor[d], 1);
        int slot = row_off[d] + pos;
        float coef = dinv[s] * dinv[d];
        eData[slot] = make_int2(s, __float_as_int(coef));
    }
}

// ---------------- MFMA GEMM: Y_bf16[n,128] = X_f32[n,128] @ W_f32[128,128] ----------------
// 256 thr = 4 waves; block tile 64 rows x 128 cols; whole K=128 in LDS.
// sA[64][128] bf16 (X tile), sWt[128][128] bf16 (W transposed), both +8 pad.
#define LDA 136
#define LDW 136
__global__ __launch_bounds__(256) void k_gemm(const float* __restrict__ X,
                                              const float* __restrict__ W,
                                              unsigned short* __restrict__ Y, int nRows) {
    __shared__ unsigned short sA[64 * LDA];    // 17.4 KB
    __shared__ unsigned short sWt[128 * LDW];  // 34.8 KB
    const int t = threadIdx.x;
    const int row0 = blockIdx.x * 64;

    // stage W -> sWt[n][k] (bf16, transposed)
#pragma unroll
    for (int rep = 0; rep < 16; ++rep) {
        int idx = t + rep * 256;
        int k = idx >> 5, n4 = (idx & 31) * 4;
        float4 v = *(const float4*)&W[(size_t)k * 128 + n4];
        sWt[(n4 + 0) * LDW + k] = f2bf(v.x);
        sWt[(n4 + 1) * LDW + k] = f2bf(v.y);
        sWt[(n4 + 2) * LDW + k] = f2bf(v.z);
        sWt[(n4 + 3) * LDW + k] = f2bf(v.w);
    }
    // stage X tile -> sA[r][k] (bf16)
#pragma unroll
    for (int rep = 0; rep < 8; ++rep) {
        int idx = t + rep * 256;
        int r = idx >> 5, k4 = (idx & 31) * 4;
        int gr = row0 + r;
        float4 v = make_float4(0.f, 0.f, 0.f, 0.f);
        if (gr < nRows) v = *(const float4*)&X[(size_t)gr * 128 + k4];
        ushort4 p;
        p.x = f2bf(v.x); p.y = f2bf(v.y); p.z = f2bf(v.z); p.w = f2bf(v.w);
        *(ushort4*)&sA[r * LDA + k4] = p;
    }
    __syncthreads();

    const int wave = t >> 6, lane = t & 63;
    const int l15 = lane & 15;
    const int koff = (lane >> 4) * 8;
    const int arow = wave * 16 + l15;

    f32x4 acc[8];
#pragma unroll
    for (int c = 0; c < 8; ++c) acc[c] = (f32x4){0.f, 0.f, 0.f, 0.f};

#pragma unroll
    for (int ks = 0; ks < 4; ++ks) {
        short8 a = *(const short8*)&sA[arow * LDA + ks * 32 + koff];
#pragma unroll
        for (int c = 0; c < 8; ++c) {
            short8 b = *(const short8*)&sWt[(c * 16 + l15) * LDW + ks * 32 + koff];
            acc[c] = __builtin_amdgcn_mfma_f32_16x16x32_bf16(a, b, acc[c], 0, 0, 0);
        }
    }
    // C/D layout: col = lane&15, row = (lane>>4)*4 + r
    const int orow = row0 + wave * 16 + (lane >> 4) * 4;
#pragma unroll
    for (int r = 0; r < 4; ++r) {
        int gr = orow + r;
        if (gr < nRows) {
#pragma unroll
            for (int c = 0; c < 8; ++c)
                Y[(size_t)gr * 128 + c * 16 + l15] = f2bf(acc[c][r]);
        }
    }
}

// ---------------- fused gather (bf16 in, f32 out) + self-loop + bias + leaky-relu ----
// 16 lanes per node, uint4 (8 bf16) per lane; 256-thread block = 16 nodes
__global__ __launch_bounds__(256) void k_gather(const uint4* __restrict__ h4,
                                                const int* __restrict__ row_off,
                                                const int2* __restrict__ eData,
                                                const float* __restrict__ dinv,
                                                const float* __restrict__ bias,
                                                float* __restrict__ out, int n) {
    const int g = threadIdx.x >> 4;
    const int l = threadIdx.x & 15;
    const int i = blockIdx.x * 16 + g;
    if (i >= n) return;
    const int beg = row_off[i], end = row_off[i + 1];
    const float d = dinv[i];
    const float dd = d * d;

    float acc[8];
    {
        uint4 hv = h4[(size_t)i * 16 + l];
        acc[0] = bf2f(hv.x & 0xFFFFu) * dd;
        acc[1] = __uint_as_float(hv.x & 0xFFFF0000u) * dd;
        acc[2] = bf2f(hv.y & 0xFFFFu) * dd;
        acc[3] = __uint_as_float(hv.y & 0xFFFF0000u) * dd;
        acc[4] = bf2f(hv.z & 0xFFFFu) * dd;
        acc[5] = __uint_as_float(hv.z & 0xFFFF0000u) * dd;
        acc[6] = bf2f(hv.w & 0xFFFFu) * dd;
        acc[7] = __uint_as_float(hv.w & 0xFFFF0000u) * dd;
    }

#define ACCUM(v, c)                                            \
    do {                                                       \
        acc[0] += bf2f((v).x & 0xFFFFu) * (c);                 \
        acc[1] += __uint_as_float((v).x & 0xFFFF0000u) * (c);  \
        acc[2] += bf2f((v).y & 0xFFFFu) * (c);                 \
        acc[3] += __uint_as_float((v).y & 0xFFFF0000u) * (c);  \
        acc[4] += bf2f((v).z & 0xFFFFu) * (c);                 \
        acc[5] += __uint_as_float((v).z & 0xFFFF0000u) * (c);  \
        acc[6] += bf2f((v).w & 0xFFFFu) * (c);                 \
        acc[7] += __uint_as_float((v).w & 0xFFFF0000u) * (c);  \
    } while (0)

    int e = beg;
    for (; e + 4 <= end; e += 4) {
        int2 m0 = eData[e];
        int2 m1 = eData[e + 1];
        int2 m2 = eData[e + 2];
        int2 m3 = eData[e + 3];
        uint4 v0 = h4[(size_t)m0.x * 16 + l];
        uint4 v1 = h4[(size_t)m1.x * 16 + l];
        uint4 v2 = h4[(size_t)m2.x * 16 + l];
        uint4 v3 = h4[(size_t)m3.x * 16 + l];
        float c0 = __int_as_float(m0.y);
        float c1 = __int_as_float(m1.y);
        float c2 = __int_as_float(m2.y);
        float c3 = __int_as_float(m3.y);
        ACCUM(v0, c0);
        ACCUM(v1, c1);
        ACCUM(v2, c2);
        ACCUM(v3, c3);
    }
    for (; e < end; ++e) {
        int2 m = eData[e];
        uint4 v = h4[(size_t)m.x * 16 + l];
        float c = __int_as_float(m.y);
        ACCUM(v, c);
    }
#undef ACCUM

    float4 b0 = *(const float4*)&bias[l * 8];
    float4 b1 = *(const float4*)&bias[l * 8 + 4];
    float4 r0, r1;
    r0.x = acc[0] + b0.x; r0.x = r0.x > 0.f ? r0.x : NEG_SLOPE * r0.x;
    r0.y = acc[1] + b0.y; r0.y = r0.y > 0.f ? r0.y : NEG_SLOPE * r0.y;
    r0.z = acc[2] + b0.z; r0.z = r0.z > 0.f ? r0.z : NEG_SLOPE * r0.z;
    r0.w = acc[3] + b0.w; r0.w = r0.w > 0.f ? r0.w : NEG_SLOPE * r0.w;
    r1.x = acc[4] + b1.x; r1.x = r1.x > 0.f ? r1.x : NEG_SLOPE * r1.x;
    r1.y = acc[5] + b1.y; r1.y = r1.y > 0.f ? r1.y : NEG_SLOPE * r1.y;
    r1.z = acc[6] + b1.z; r1.z = r1.z > 0.f ? r1.z : NEG_SLOPE * r1.z;
    r1.w = acc[7] + b1.w; r1.w = r1.w > 0.f ? r1.w : NEG_SLOPE * r1.w;
    *(float4*)&out[(size_t)i * 128 + l * 8] = r0;
    *(float4*)&out[(size_t)i * 128 + l * 8 + 4] = r1;
}

// ---------------- per-graph node counts ----------------
__global__ void k_gcnt(const int* __restrict__ batch, int* __restrict__ gcnt, int n) {
    int i = blockIdx.x * blockDim.x + threadIdx.x;
    if (i < n) atomicAdd(&gcnt[batch[i]], 1);
}

// ---------------- segmented mean pool (batch sorted, f32 in) ----------------
__global__ __launch_bounds__(128) void k_pool(const float* __restrict__ h,
                                              const int* __restrict__ gOff,
                                              float* __restrict__ out, int nG) {
    int g = blockIdx.x;
    int c = threadIdx.x;
    int beg = gOff[g], end = gOff[g + 1];
    float acc = 0.0f;
    for (int r = beg; r < end; ++r) acc += h[(size_t)r * DIM + c];
    float cntf = (float)(end - beg);
    out[(size_t)g * DIM + c] = acc / fmaxf(cntf, 1.0f);
}

static inline void run_scan(const int* cnt, int* bsum, int* off, int n,
                            hipStream_t stream) {
    int nb = (n + 255) / 256;
    k_scan1<<<nb, 256, 0, stream>>>(cnt, bsum, n);
    k_scan2<<<1, 1024, 0, stream>>>(bsum, nb);
    k_scan3<<<nb, 256, 0, stream>>>(cnt, bsum, off, n);
}

extern "C" void kernel_launch(void* const* d_in, const int* in_sizes, int n_in,
                              void* d_out, int out_size, void* d_ws, size_t ws_size,
                              hipStream_t stream) {
    const float* X  = (const float*)d_in[0];
    const float* W1 = (const float*)d_in[1];
    const float* b1 = (const float*)d_in[2];
    const float* W2 = (const float*)d_in[3];
    const float* b2 = (const float*)d_in[4];
    const int*   ei = (const int*)d_in[5];
    const int*   batch = (const int*)d_in[6];
    float* out = (float*)d_out;

    const int NN = in_sizes[0] / DIM;     // 50000
    const int NE = in_sizes[5] / 2;       // 600000
    const int NG = out_size / DIM;        // 1000

    const int* src = ei;
    const int* dst = ei + NE;

    char* ws = (char*)d_ws;
    size_t o = 0;
    auto alloc = [&](size_t bytes) {
        char* p = ws + o;
        o += (bytes + 1023) & ~(size_t)1023;
        return p;
    };
    int*   cnt     = (int*)alloc((size_t)NN * 4);
    int*   cursor  = (int*)alloc((size_t)NN * 4);
    int*   row_off = (int*)alloc((size_t)(NN + 1) * 4);
    float* dinv    = (float*)alloc((size_t)NN * 4);
    int*   bsum    = (int*)alloc((size_t)1024 * 4);
    int*   gcnt    = (int*)alloc((size_t)NG * 4);
    int*   gOff    = (int*)alloc((size_t)(NG + 1) * 4);
    int2*  eData   = (int2*)alloc((size_t)NE * 8);
    unsigned short* bufH = (unsigned short*)alloc((size_t)NN * DIM * 2);  // bf16
    float* bufAgg  = (float*)alloc((size_t)NN * DIM * 4);                 // f32

    hipMemsetAsync(cnt, 0, (size_t)NN * 4, stream);
    hipMemsetAsync(cursor, 0, (size_t)NN * 4, stream);
    hipMemsetAsync(gcnt, 0, (size_t)NG * 4, stream);

    const int B = 256;
    // ---- CSR build (shared by both layers) ----
    k_degi<<<(NE + B - 1) / B, B, 0, stream>>>(dst, cnt, NE);
    run_scan(cnt, bsum, row_off, NN, stream);
    k_dinv<<<(NN + B - 1) / B, B, 0, stream>>>(cnt, dinv, NN);
    k_fill<<<(NE + B - 1) / B, B, 0, stream>>>(src, dst, row_off, cursor, dinv,
                                               eData, NE);
    // ---- graph offsets for pooling ----
    k_gcnt<<<(NN + B - 1) / B, B, 0, stream>>>(batch, gcnt, NN);
    run_scan(gcnt, bsum, gOff, NG, stream);

    int gemm_grid = (NN + 63) / 64;
    int gather_grid = (NN + 15) / 16;

    // ---- layer 1 ----
    k_gemm<<<gemm_grid, B, 0, stream>>>(X, W1, bufH, NN);
    k_gather<<<gather_grid, B, 0, stream>>>((const uint4*)bufH, row_off, eData,
                                            dinv, b1, bufAgg, NN);

    // ---- layer 2 ----
    k_gemm<<<gemm_grid, B, 0, stream>>>(bufAgg, W2, bufH, NN);
    k_gather<<<gather_grid, B, 0, stream>>>((const uint4*)bufH, row_off, eData,
                                            dinv, b2, bufAgg, NN);

    // ---- global mean pool ----
    k_pool<<<NG, 128, 0, stream>>>(bufAgg, gOff, out, NG);
}

// Round 7
// 283.389 us; speedup vs baseline: 2.8458x; 1.0372x over previous
//
#include <hip/hip_runtime.h>

#define DIM 128
#define NEG_SLOPE 0.01f

typedef short short8 __attribute__((ext_vector_type(8)));
typedef float f32x4 __attribute__((ext_vector_type(4)));

// round-to-nearest-even f32 -> bf16 (as ushort)
__device__ __forceinline__ unsigned short f2bf(float f) {
    unsigned u = __float_as_uint(f);
    u = u + 0x7FFFu + ((u >> 16) & 1u);
    return (unsigned short)(u >> 16);
}
__device__ __forceinline__ float bf2f(unsigned short s) {
    return __uint_as_float((unsigned)s << 16);
}

// ---------------- fused degree + per-graph counts ----------------
__global__ void k_counts(const int* __restrict__ dst, const int* __restrict__ batch,
                         int* __restrict__ cnt, int* __restrict__ gcnt,
                         int nE, int nN) {
    int i = blockIdx.x * blockDim.x + threadIdx.x;
    if (i < nE) atomicAdd(&cnt[dst[i]], 1);
    if (i < nN) atomicAdd(&gcnt[batch[i]], 1);
}

// ---------------- fused 3-pass scan over TWO arrays (cnt->row_off, gcnt->gOff) ----
__global__ __launch_bounds__(256) void k_scan1f(const int* __restrict__ cnt,
                                                const int* __restrict__ gcnt,
                                                int* __restrict__ bsum,
                                                int* __restrict__ bsum2,
                                                int n1, int n2, int nb1) {
    __shared__ int sh[256];
    const int b = blockIdx.x, t = threadIdx.x;
    const bool segA = b < nb1;
    const int* srcA = segA ? cnt : gcnt;
    const int n = segA ? n1 : n2;
    const int bb = segA ? b : b - nb1;
    int i = bb * 256 + t;
    sh[t] = (i < n) ? srcA[i] : 0;
    __syncthreads();
#pragma unroll
    for (int s = 128; s > 0; s >>= 1) {
        if (t < s) sh[t] += sh[t + s];
        __syncthreads();
    }
    if (t == 0) (segA ? bsum : bsum2)[bb] = sh[0];
}

__global__ __launch_bounds__(1024) void k_scan2f(int* __restrict__ bsum,
                                                 int* __restrict__ bsum2,
                                                 int nb1, int nb2) {
    __shared__ int sh[1024];
    int t = threadIdx.x;
    // segment A
    int v = (t < nb1) ? bsum[t] : 0;
    sh[t] = v;
    __syncthreads();
    for (int s = 1; s < 1024; s <<= 1) {
        int u = (t >= s) ? sh[t - s] : 0;
        __syncthreads();
        sh[t] += u;
        __syncthreads();
    }
    if (t < nb1) bsum[t] = sh[t] - v;
    __syncthreads();
    // segment B
    int v2 = (t < nb2) ? bsum2[t] : 0;
    sh[t] = v2;
    __syncthreads();
    for (int s = 1; s < 1024; s <<= 1) {
        int u = (t >= s) ? sh[t - s] : 0;
        __syncthreads();
        sh[t] += u;
        __syncthreads();
    }
    if (t < nb2) bsum2[t] = sh[t] - v2;
}

// pass 3 + dinv (segment A only)
__global__ __launch_bounds__(256) void k_scan3f(const int* __restrict__ cnt,
                                                const int* __restrict__ gcnt,
                                                const int* __restrict__ bsum,
                                                const int* __restrict__ bsum2,
                                                int* __restrict__ row_off,
                                                int* __restrict__ gOff,
                                                float* __restrict__ dinv,
                                                int n1, int n2, int nb1) {
    __shared__ int sh[256];
    const int b = blockIdx.x, t = threadIdx.x;
    const bool segA = b < nb1;
    const int* srcA = segA ? cnt : gcnt;
    const int* bs = segA ? bsum : bsum2;
    int* off = segA ? row_off : gOff;
    const int n = segA ? n1 : n2;
    const int bb = segA ? b : b - nb1;
    int i = bb * 256 + t;
    int v = (i < n) ? srcA[i] : 0;
    sh[t] = v;
    __syncthreads();
    for (int s = 1; s < 256; s <<= 1) {
        int u = (t >= s) ? sh[t - s] : 0;
        __syncthreads();
        sh[t] += u;
        __syncthreads();
    }
    int incl = sh[t];
    int base = bs[bb];
    if (i < n) off[i] = base + incl - v;
    if (i == n - 1) off[n] = base + incl;
    if (segA && i < n) dinv[i] = rsqrtf((float)v + 1.0f);
}

// ---------------- CSR fill ----------------
__global__ void k_fill(const int* __restrict__ src, const int* __restrict__ dst,
                       const int* __restrict__ row_off, int* __restrict__ cursor,
                       const float* __restrict__ dinv,
                       int2* __restrict__ eData, int nE) {
    int e = blockIdx.x * blockDim.x + threadIdx.x;
    if (e < nE) {
        int s = src[e], d = dst[e];
        int pos = atomicAdd(&cursor[d], 1);
        int slot = row_off[d] + pos;
        float coef = dinv[s] * dinv[d];
        eData[slot] = make_int2(s, __float_as_int(coef));
    }
}

// ---------------- MFMA GEMM: Y_bf16[n,128] = X_f32[n,128] @ W_f32[128,128] ---------
#define LDA 136
#define LDW 136
__global__ __launch_bounds__(256) void k_gemm(const float* __restrict__ X,
                                              const float* __restrict__ W,
                                              unsigned short* __restrict__ Y, int nRows) {
    __shared__ unsigned short sA[64 * LDA];    // 17.4 KB
    __shared__ unsigned short sWt[128 * LDW];  // 34.8 KB
    const int t = threadIdx.x;
    const int row0 = blockIdx.x * 64;

    // stage W -> sWt[n][k] (bf16, transposed)
#pragma unroll
    for (int rep = 0; rep < 16; ++rep) {
        int idx = t + rep * 256;
        int k = idx >> 5, n4 = (idx & 31) * 4;
        float4 v = *(const float4*)&W[(size_t)k * 128 + n4];
        sWt[(n4 + 0) * LDW + k] = f2bf(v.x);
        sWt[(n4 + 1) * LDW + k] = f2bf(v.y);
        sWt[(n4 + 2) * LDW + k] = f2bf(v.z);
        sWt[(n4 + 3) * LDW + k] = f2bf(v.w);
    }
    // stage X tile -> sA[r][k] (bf16)
#pragma unroll
    for (int rep = 0; rep < 8; ++rep) {
        int idx = t + rep * 256;
        int r = idx >> 5, k4 = (idx & 31) * 4;
        int gr = row0 + r;
        float4 v = make_float4(0.f, 0.f, 0.f, 0.f);
        if (gr < nRows) v = *(const float4*)&X[(size_t)gr * 128 + k4];
        ushort4 p;
        p.x = f2bf(v.x); p.y = f2bf(v.y); p.z = f2bf(v.z); p.w = f2bf(v.w);
        *(ushort4*)&sA[r * LDA + k4] = p;
    }
    __syncthreads();

    const int wave = t >> 6, lane = t & 63;
    const int l15 = lane & 15;
    const int koff = (lane >> 4) * 8;
    const int arow = wave * 16 + l15;

    f32x4 acc[8];
#pragma unroll
    for (int c = 0; c < 8; ++c) acc[c] = (f32x4){0.f, 0.f, 0.f, 0.f};

#pragma unroll
    for (int ks = 0; ks < 4; ++ks) {
        short8 a = *(const short8*)&sA[arow * LDA + ks * 32 + koff];
#pragma unroll
        for (int c = 0; c < 8; ++c) {
            short8 b = *(const short8*)&sWt[(c * 16 + l15) * LDW + ks * 32 + koff];
            acc[c] = __builtin_amdgcn_mfma_f32_16x16x32_bf16(a, b, acc[c], 0, 0, 0);
        }
    }
    const int orow = row0 + wave * 16 + (lane >> 4) * 4;
#pragma unroll
    for (int r = 0; r < 4; ++r) {
        int gr = orow + r;
        if (gr < nRows) {
#pragma unroll
            for (int c = 0; c < 8; ++c)
                Y[(size_t)gr * 128 + c * 16 + l15] = f2bf(acc[c][r]);
        }
    }
}

// ---------------- fused gather (bf16 in, f32 out) + self-loop + bias + leaky-relu ----
// 16 lanes per node, uint4 (8 bf16) per lane; 256-thread block = 16 nodes; 8-way MLP
__global__ __launch_bounds__(256) void k_gather(const uint4* __restrict__ h4,
                                                const int* __restrict__ row_off,
                                                const int2* __restrict__ eData,
                                                const float* __restrict__ dinv,
                                                const float* __restrict__ bias,
                                                float* __restrict__ out, int n) {
    const int g = threadIdx.x >> 4;
    const int l = threadIdx.x & 15;
    const int i = blockIdx.x * 16 + g;
    if (i >= n) return;
    const int beg = row_off[i], end = row_off[i + 1];
    const float d = dinv[i];
    const float dd = d * d;

    float acc[8];
    {
        uint4 hv = h4[(size_t)i * 16 + l];
        acc[0] = bf2f(hv.x & 0xFFFFu) * dd;
        acc[1] = __uint_as_float(hv.x & 0xFFFF0000u) * dd;
        acc[2] = bf2f(hv.y & 0xFFFFu) * dd;
        acc[3] = __uint_as_float(hv.y & 0xFFFF0000u) * dd;
        acc[4] = bf2f(hv.z & 0xFFFFu) * dd;
        acc[5] = __uint_as_float(hv.z & 0xFFFF0000u) * dd;
        acc[6] = bf2f(hv.w & 0xFFFFu) * dd;
        acc[7] = __uint_as_float(hv.w & 0xFFFF0000u) * dd;
    }

#define ACCUM(v, c)                                            \
    do {                                                       \
        acc[0] += bf2f((v).x & 0xFFFFu) * (c);                 \
        acc[1] += __uint_as_float((v).x & 0xFFFF0000u) * (c);  \
        acc[2] += bf2f((v).y & 0xFFFFu) * (c);                 \
        acc[3] += __uint_as_float((v).y & 0xFFFF0000u) * (c);  \
        acc[4] += bf2f((v).z & 0xFFFFu) * (c);                 \
        acc[5] += __uint_as_float((v).z & 0xFFFF0000u) * (c);  \
        acc[6] += bf2f((v).w & 0xFFFFu) * (c);                 \
        acc[7] += __uint_as_float((v).w & 0xFFFF0000u) * (c);  \
    } while (0)

    int e = beg;
    for (; e + 8 <= end; e += 8) {
        int2 m[8];
        uint4 v[8];
#pragma unroll
        for (int j = 0; j < 8; ++j) m[j] = eData[e + j];
#pragma unroll
        for (int j = 0; j < 8; ++j) v[j] = h4[(size_t)m[j].x * 16 + l];
#pragma unroll
        for (int j = 0; j < 8; ++j) {
            float c = __int_as_float(m[j].y);
            ACCUM(v[j], c);
        }
    }
    for (; e + 2 <= end; e += 2) {
        int2 m0 = eData[e], m1 = eData[e + 1];
        uint4 v0 = h4[(size_t)m0.x * 16 + l];
        uint4 v1 = h4[(size_t)m1.x * 16 + l];
        float c0 = __int_as_float(m0.y), c1 = __int_as_float(m1.y);
        ACCUM(v0, c0);
        ACCUM(v1, c1);
    }
    for (; e < end; ++e) {
        int2 m = eData[e];
        uint4 v = h4[(size_t)m.x * 16 + l];
        float c = __int_as_float(m.y);
        ACCUM(v, c);
    }
#undef ACCUM

    float4 b0 = *(const float4*)&bias[l * 8];
    float4 b1 = *(const float4*)&bias[l * 8 + 4];
    float4 r0, r1;
    r0.x = acc[0] + b0.x; r0.x = r0.x > 0.f ? r0.x : NEG_SLOPE * r0.x;
    r0.y = acc[1] + b0.y; r0.y = r0.y > 0.f ? r0.y : NEG_SLOPE * r0.y;
    r0.z = acc[2] + b0.z; r0.z = r0.z > 0.f ? r0.z : NEG_SLOPE * r0.z;
    r0.w = acc[3] + b0.w; r0.w = r0.w > 0.f ? r0.w : NEG_SLOPE * r0.w;
    r1.x = acc[4] + b1.x; r1.x = r1.x > 0.f ? r1.x : NEG_SLOPE * r1.x;
    r1.y = acc[5] + b1.y; r1.y = r1.y > 0.f ? r1.y : NEG_SLOPE * r1.y;
    r1.z = acc[6] + b1.z; r1.z = r1.z > 0.f ? r1.z : NEG_SLOPE * r1.z;
    r1.w = acc[7] + b1.w; r1.w = r1.w > 0.f ? r1.w : NEG_SLOPE * r1.w;
    *(float4*)&out[(size_t)i * 128 + l * 8] = r0;
    *(float4*)&out[(size_t)i * 128 + l * 8 + 4] = r1;
}

// ---------------- segmented mean pool (batch sorted, f32 in) ----------------
__global__ __launch_bounds__(128) void k_pool(const float* __restrict__ h,
                                              const int* __restrict__ gOff,
                                              float* __restrict__ out, int nG) {
    int g = blockIdx.x;
    int c = threadIdx.x;
    int beg = gOff[g], end = gOff[g + 1];
    float acc = 0.0f;
    for (int r = beg; r < end; ++r) acc += h[(size_t)r * DIM + c];
    float cntf = (float)(end - beg);
    out[(size_t)g * DIM + c] = acc / fmaxf(cntf, 1.0f);
}

extern "C" void kernel_launch(void* const* d_in, const int* in_sizes, int n_in,
                              void* d_out, int out_size, void* d_ws, size_t ws_size,
                              hipStream_t stream) {
    const float* X  = (const float*)d_in[0];
    const float* W1 = (const float*)d_in[1];
    const float* b1 = (const float*)d_in[2];
    const float* W2 = (const float*)d_in[3];
    const float* b2 = (const float*)d_in[4];
    const int*   ei = (const int*)d_in[5];
    const int*   batch = (const int*)d_in[6];
    float* out = (float*)d_out;

    const int NN = in_sizes[0] / DIM;     // 50000
    const int NE = in_sizes[5] / 2;       // 600000
    const int NG = out_size / DIM;        // 1000

    const int* src = ei;
    const int* dst = ei + NE;

    char* ws = (char*)d_ws;
    size_t o = 0;
    auto alloc = [&](size_t bytes) {
        char* p = ws + o;
        o += (bytes + 1023) & ~(size_t)1023;
        return p;
    };
    // zero-init region: cnt | cursor | gcnt contiguous -> ONE memset
    int* zbase = (int*)alloc((size_t)(2 * NN + NG) * 4);
    int* cnt = zbase;
    int* cursor = zbase + NN;
    int* gcnt = zbase + 2 * NN;
    int*   row_off = (int*)alloc((size_t)(NN + 1) * 4);
    float* dinv    = (float*)alloc((size_t)NN * 4);
    int*   bsum    = (int*)alloc((size_t)1024 * 4);
    int*   bsum2   = (int*)alloc((size_t)1024 * 4);
    int*   gOff    = (int*)alloc((size_t)(NG + 1) * 4);
    int2*  eData   = (int2*)alloc((size_t)NE * 8);
    unsigned short* bufH = (unsigned short*)alloc((size_t)NN * DIM * 2);  // bf16
    float* bufAgg  = (float*)alloc((size_t)NN * DIM * 4);                 // f32

    hipMemsetAsync(zbase, 0, (size_t)(2 * NN + NG) * 4, stream);

    const int B = 256;
    const int nb1 = (NN + 255) / 256;
    const int nb2 = (NG + 255) / 256;

    // ---- counts (degree + graph sizes) in one launch ----
    k_counts<<<(NE + B - 1) / B, B, 0, stream>>>(dst, batch, cnt, gcnt, NE, NN);
    // ---- fused scans (row_off, gOff) + dinv ----
    k_scan1f<<<nb1 + nb2, B, 0, stream>>>(cnt, gcnt, bsum, bsum2, NN, NG, nb1);
    k_scan2f<<<1, 1024, 0, stream>>>(bsum, bsum2, nb1, nb2);
    k_scan3f<<<nb1 + nb2, B, 0, stream>>>(cnt, gcnt, bsum, bsum2, row_off, gOff,
                                          dinv, NN, NG, nb1);
    // ---- CSR fill ----
    k_fill<<<(NE + B - 1) / B, B, 0, stream>>>(src, dst, row_off, cursor, dinv,
                                               eData, NE);

    int gemm_grid = (NN + 63) / 64;
    int gather_grid = (NN + 15) / 16;

    // ---- layer 1 ----
    k_gemm<<<gemm_grid, B, 0, stream>>>(X, W1, bufH, NN);
    k_gather<<<gather_grid, B, 0, stream>>>((const uint4*)bufH, row_off, eData,
                                            dinv, b1, bufAgg, NN);

    // ---- layer 2 ----
    k_gemm<<<gemm_grid, B, 0, stream>>>(bufAgg, W2, bufH, NN);
    k_gather<<<gather_grid, B, 0, stream>>>((const uint4*)bufH, row_off, eData,
                                            dinv, b2, bufAgg, NN);

    // ---- global mean pool ----
    k_pool<<<NG, 128, 0, stream>>>(bufAgg, gOff, out, NG);
}